// Round 1
// baseline (25394.714 us; speedup 1.0000x reference)
//
#include <hip/hip_runtime.h>

#define N_NODES 50000
#define N_EDGES 400000
#define DIM 512
#define N_LAYERS 4
#define N_GRAPHS 500
#define EPS_F 1e-5f
#define NEG 0.01f

__device__ __forceinline__ float leaky(float x) { return x >= 0.f ? x : NEG * x; }

// ---------------- scatter-add: aggr[dst] += h[src] ----------------
// one wave per edge; lane handles 8 consecutive floats (64*8 = 512)
__global__ __launch_bounds__(256) void scatter_add_k(
    const int* __restrict__ ei, const float* __restrict__ h, int hstride,
    float* __restrict__ aggr)
{
    int e = blockIdx.x * 4 + (threadIdx.x >> 6);
    if (e >= N_EDGES) return;
    int lane = threadIdx.x & 63;
    int src = ei[e];
    int dst = ei[N_EDGES + e];
    const float* hp = h + (size_t)src * hstride + lane * 8;
    float* ap = aggr + (size_t)dst * DIM + lane * 8;
    float4 v0 = *(const float4*)hp;
    float4 v1 = *(const float4*)(hp + 4);
    atomicAdd(ap + 0, v0.x); atomicAdd(ap + 1, v0.y);
    atomicAdd(ap + 2, v0.z); atomicAdd(ap + 3, v0.w);
    atomicAdd(ap + 4, v1.x); atomicAdd(ap + 5, v1.y);
    atomicAdd(ap + 6, v1.z); atomicAdd(ap + 7, v1.w);
}

// ---------------- fused GEMM: C = leaky((A1 [+A2]) @ B + bias) ----------------
// 128x128 tile, K-step 16, 256 threads (16x16), 8x8 accum per thread.
__global__ __launch_bounds__(256) void gemm_k(
    const float* __restrict__ A1, int lda1,
    const float* __restrict__ A2,        // nullable, row stride DIM
    const float* __restrict__ B,         // [DIM][DIM] row-major
    const float* __restrict__ bias,      // [DIM]
    float* __restrict__ C, int ldc, int M)
{
    __shared__ float As[16][132];        // [k][m], +4 pad kills 4-way store conflict
    __shared__ float Bs[16][128];        // [k][n]
    const int tid = threadIdx.x;
    const int tx = tid & 15, ty = tid >> 4;
    const int row0 = blockIdx.x * 128;
    const int col0 = blockIdx.y * 128;

    float acc[8][8];
#pragma unroll
    for (int i = 0; i < 8; ++i)
#pragma unroll
        for (int j = 0; j < 8; ++j) acc[i][j] = 0.f;

    const int aRow = tid >> 2;           // 0..63
    const int aCol = (tid & 3) << 2;     // 0,4,8,12
    const int bRow = tid >> 5;           // 0..7
    const int bCol = (tid & 31) << 2;    // 0..124

    for (int k0 = 0; k0 < DIM; k0 += 16) {
#pragma unroll
        for (int half = 0; half < 2; ++half) {
            int r = aRow + half * 64;
            int grow = row0 + r;
            float4 v = make_float4(0.f, 0.f, 0.f, 0.f);
            if (grow < M) {
                v = *(const float4*)(A1 + (size_t)grow * lda1 + k0 + aCol);
                if (A2) {
                    float4 w = *(const float4*)(A2 + (size_t)grow * DIM + k0 + aCol);
                    v.x += w.x; v.y += w.y; v.z += w.z; v.w += w.w;
                }
            }
            As[aCol + 0][r] = v.x; As[aCol + 1][r] = v.y;
            As[aCol + 2][r] = v.z; As[aCol + 3][r] = v.w;
        }
#pragma unroll
        for (int half = 0; half < 2; ++half) {
            int kr = bRow + half * 8;
            *(float4*)&Bs[kr][bCol] =
                *(const float4*)(B + (size_t)(k0 + kr) * DIM + col0 + bCol);
        }
        __syncthreads();
#pragma unroll
        for (int k = 0; k < 16; ++k) {
            float a[8], b[8];
            *(float4*)&a[0] = *(const float4*)&As[k][ty * 8];
            *(float4*)&a[4] = *(const float4*)&As[k][ty * 8 + 4];
            *(float4*)&b[0] = *(const float4*)&Bs[k][tx * 8];
            *(float4*)&b[4] = *(const float4*)&Bs[k][tx * 8 + 4];
#pragma unroll
            for (int i = 0; i < 8; ++i)
#pragma unroll
                for (int j = 0; j < 8; ++j)
                    acc[i][j] = fmaf(a[i], b[j], acc[i][j]);
        }
        __syncthreads();
    }

    const int cc = col0 + tx * 8;
    float bb[8];
    *(float4*)&bb[0] = *(const float4*)(bias + cc);
    *(float4*)&bb[4] = *(const float4*)(bias + cc + 4);
#pragma unroll
    for (int i = 0; i < 8; ++i) {
        int grow = row0 + ty * 8 + i;
        if (grow < M) {
            float o[8];
#pragma unroll
            for (int j = 0; j < 8; ++j) o[j] = leaky(acc[i][j] + bb[j]);
            *(float4*)(C + (size_t)grow * ldc + cc) = *(float4*)&o[0];
            *(float4*)(C + (size_t)grow * ldc + cc + 4) = *(float4*)&o[4];
        }
    }
}

// ------- NodeNorm (in place) + per-block BatchNorm partial stats -------
// one wave per row-chunk; lane owns cols {4l..4l+3, 256+4l..256+4l+3}
__global__ __launch_bounds__(256) void nodenorm_k(
    float* __restrict__ z, float* __restrict__ partials /* [gridDim.x][1024] */)
{
    __shared__ float part[1024];
    for (int t = threadIdx.x; t < 1024; t += 256) part[t] = 0.f;
    __syncthreads();

    int wave = blockIdx.x * 4 + (threadIdx.x >> 6);
    int lane = threadIdx.x & 63;
    int nw = gridDim.x * 4;
    int per = (N_NODES + nw - 1) / nw;
    int r0 = wave * per;
    int r1 = min(N_NODES, r0 + per);

    float cs[8] = {0, 0, 0, 0, 0, 0, 0, 0};
    float cq[8] = {0, 0, 0, 0, 0, 0, 0, 0};

    for (int r = r0; r < r1; ++r) {
        float* p = z + (size_t)r * DIM;
        float4 a = *(const float4*)(p + lane * 4);
        float4 b = *(const float4*)(p + 256 + lane * 4);
        float s = a.x + a.y + a.z + a.w + b.x + b.y + b.z + b.w;
        float q = a.x * a.x + a.y * a.y + a.z * a.z + a.w * a.w
                + b.x * b.x + b.y * b.y + b.z * b.z + b.w * b.w;
#pragma unroll
        for (int off = 32; off; off >>= 1) {
            s += __shfl_xor(s, off);
            q += __shfl_xor(q, off);
        }
        float mean = s * (1.f / DIM);
        float var = q * (1.f / DIM) - mean * mean;
        float rs = rsqrtf(var + EPS_F);
        a.x = (a.x - mean) * rs; a.y = (a.y - mean) * rs;
        a.z = (a.z - mean) * rs; a.w = (a.w - mean) * rs;
        b.x = (b.x - mean) * rs; b.y = (b.y - mean) * rs;
        b.z = (b.z - mean) * rs; b.w = (b.w - mean) * rs;
        *(float4*)(p + lane * 4) = a;
        *(float4*)(p + 256 + lane * 4) = b;
        cs[0] += a.x; cs[1] += a.y; cs[2] += a.z; cs[3] += a.w;
        cs[4] += b.x; cs[5] += b.y; cs[6] += b.z; cs[7] += b.w;
        cq[0] += a.x * a.x; cq[1] += a.y * a.y; cq[2] += a.z * a.z; cq[3] += a.w * a.w;
        cq[4] += b.x * b.x; cq[5] += b.y * b.y; cq[6] += b.z * b.z; cq[7] += b.w * b.w;
    }
#pragma unroll
    for (int i = 0; i < 4; ++i) {
        atomicAdd(&part[lane * 4 + i], cs[i]);
        atomicAdd(&part[256 + lane * 4 + i], cs[4 + i]);
        atomicAdd(&part[512 + lane * 4 + i], cq[i]);
        atomicAdd(&part[768 + lane * 4 + i], cq[4 + i]);
    }
    __syncthreads();
    float* dst = partials + (size_t)blockIdx.x * 1024;
    *(float4*)(dst + threadIdx.x * 4) = *(const float4*)&part[threadIdx.x * 4];
}

// ------- BatchNorm finalize: scale/shift per column -------
__global__ void bn_finalize_k(
    const float* __restrict__ partials, int nblocks,
    const float* __restrict__ gamma, const float* __restrict__ beta,
    float* __restrict__ sc, float* __restrict__ sh)
{
    int c = blockIdx.x * blockDim.x + threadIdx.x;
    if (c >= DIM) return;
    float s = 0.f, q = 0.f;
#pragma unroll 8
    for (int b = 0; b < nblocks; ++b) {
        s += partials[(size_t)b * 1024 + c];
        q += partials[(size_t)b * 1024 + 512 + c];
    }
    float mean = s * (1.f / N_NODES);
    float var = q * (1.f / N_NODES) - mean * mean;
    float sf = gamma[c] * rsqrtf(var + EPS_F);
    sc[c] = sf;
    sh[c] = beta[c] - mean * sf;
}

// ------- BatchNorm apply + x_local write + sorted-segment pooling -------
__global__ __launch_bounds__(256) void apply_pool_k(
    const float* __restrict__ z, const float* __restrict__ sc, const float* __restrict__ sh,
    const int* __restrict__ batch,
    float* __restrict__ xloc,   // d_out local base + layer*DIM, row stride 2048
    float* __restrict__ xglob)  // d_out global base + layer*DIM, row stride 2048
{
    int wave = blockIdx.x * 4 + (threadIdx.x >> 6);
    int lane = threadIdx.x & 63;
    int nw = gridDim.x * 4;
    int per = (N_NODES + nw - 1) / nw;
    int r0 = wave * per;
    int r1 = min(N_NODES, r0 + per);
    if (r0 >= r1) return;

    float4 s0 = *(const float4*)(sc + lane * 4);
    float4 s1 = *(const float4*)(sc + 256 + lane * 4);
    float4 t0 = *(const float4*)(sh + lane * 4);
    float4 t1 = *(const float4*)(sh + 256 + lane * 4);

    float pa[8] = {0, 0, 0, 0, 0, 0, 0, 0};
    int curg = batch[r0];
    const int LD = N_LAYERS * DIM; // 2048

    for (int r = r0; r < r1; ++r) {
        int g = batch[r];
        if (g != curg) {
#pragma unroll
            for (int i = 0; i < 4; ++i) {
                atomicAdd(xglob + (size_t)curg * LD + lane * 4 + i, pa[i]);
                atomicAdd(xglob + (size_t)curg * LD + 256 + lane * 4 + i, pa[4 + i]);
                pa[i] = 0.f; pa[4 + i] = 0.f;
            }
            curg = g;
        }
        const float* p = z + (size_t)r * DIM;
        float4 a = *(const float4*)(p + lane * 4);
        float4 b = *(const float4*)(p + 256 + lane * 4);
        a.x = fmaf(a.x, s0.x, t0.x); a.y = fmaf(a.y, s0.y, t0.y);
        a.z = fmaf(a.z, s0.z, t0.z); a.w = fmaf(a.w, s0.w, t0.w);
        b.x = fmaf(b.x, s1.x, t1.x); b.y = fmaf(b.y, s1.y, t1.y);
        b.z = fmaf(b.z, s1.z, t1.z); b.w = fmaf(b.w, s1.w, t1.w);
        *(float4*)(xloc + (size_t)r * LD + lane * 4) = a;
        *(float4*)(xloc + (size_t)r * LD + 256 + lane * 4) = b;
        pa[0] += a.x; pa[1] += a.y; pa[2] += a.z; pa[3] += a.w;
        pa[4] += b.x; pa[5] += b.y; pa[6] += b.z; pa[7] += b.w;
    }
#pragma unroll
    for (int i = 0; i < 4; ++i) {
        atomicAdd(xglob + (size_t)curg * LD + lane * 4 + i, pa[i]);
        atomicAdd(xglob + (size_t)curg * LD + 256 + lane * 4 + i, pa[4 + i]);
    }
}

extern "C" void kernel_launch(void* const* d_in, const int* in_sizes, int n_in,
                              void* d_out, int out_size, void* d_ws, size_t ws_size,
                              hipStream_t stream)
{
    const float* x     = (const float*)d_in[0];
    const int*   ei    = (const int*)d_in[1];
    const int*   batch = (const int*)d_in[2];
    const float* W1    = (const float*)d_in[3];
    const float* b1    = (const float*)d_in[4];
    const float* W2    = (const float*)d_in[5];
    const float* b2    = (const float*)d_in[6];
    const float* gamma = (const float*)d_in[7];
    const float* beta  = (const float*)d_in[8];

    float* out = (float*)d_out;
    const size_t XG = (size_t)N_GRAPHS * N_LAYERS * DIM;  // 1,024,000
    float* xglob_base = out;
    float* xloc_base  = out + XG;

    const size_t NODE_BUF = (size_t)N_NODES * DIM;        // 25.6M floats
    const int NN_BLOCKS = 256;
    float* bufA     = (float*)d_ws;                        // aggr, then z2/z3
    float* bufB     = bufA + NODE_BUF;                     // z1
    float* partials = bufB + NODE_BUF;                     // [NN_BLOCKS][1024]
    float* sc       = partials + (size_t)NN_BLOCKS * 1024;
    float* sh       = sc + DIM;

    hipMemsetAsync(xglob_base, 0, XG * sizeof(float), stream);

    for (int i = 0; i < N_LAYERS; ++i) {
        const float* h;
        int hstride;
        if (i == 0) { h = x; hstride = DIM; }
        else        { h = xloc_base + (size_t)(i - 1) * DIM; hstride = N_LAYERS * DIM; }

        hipMemsetAsync(bufA, 0, NODE_BUF * sizeof(float), stream);

        scatter_add_k<<<N_EDGES / 4, 256, 0, stream>>>(ei, h, hstride, bufA);

        gemm_k<<<dim3((N_NODES + 127) / 128, DIM / 128), 256, 0, stream>>>(
            h, hstride, bufA, W1 + (size_t)i * DIM * DIM, b1 + (size_t)i * DIM,
            bufB, DIM, N_NODES);

        gemm_k<<<dim3((N_NODES + 127) / 128, DIM / 128), 256, 0, stream>>>(
            bufB, DIM, nullptr, W2 + (size_t)i * DIM * DIM, b2 + (size_t)i * DIM,
            bufA, DIM, N_NODES);

        nodenorm_k<<<NN_BLOCKS, 256, 0, stream>>>(bufA, partials);

        bn_finalize_k<<<2, 256, 0, stream>>>(partials, NN_BLOCKS,
            gamma + (size_t)i * DIM, beta + (size_t)i * DIM, sc, sh);

        apply_pool_k<<<512, 256, 0, stream>>>(bufA, sc, sh, batch,
            xloc_base + (size_t)i * DIM, xglob_base + (size_t)i * DIM);
    }
}

// Round 2
// 4064.632 us; speedup vs baseline: 6.2477x; 6.2477x over previous
//
#include <hip/hip_runtime.h>

#define N_NODES 50000
#define N_EDGES 400000
#define DIM 512
#define N_LAYERS 4
#define N_GRAPHS 500
#define EPS_F 1e-5f
#define NEG 0.01f

__device__ __forceinline__ float leaky(float x) { return x >= 0.f ? x : NEG * x; }

// ---------------- CSR build: histogram of dst ----------------
__global__ __launch_bounds__(256) void hist_k(const int* __restrict__ ei, int* __restrict__ deg)
{
    int e = blockIdx.x * 256 + threadIdx.x;
    if (e < N_EDGES) atomicAdd(&deg[ei[N_EDGES + e]], 1);
}

// ---------------- CSR build: exclusive scan (single block) ----------------
__global__ __launch_bounds__(1024) void scan_k(const int* __restrict__ deg,
                                               int* __restrict__ off, int* __restrict__ cursor)
{
    __shared__ int sums[1024];
    const int t = threadIdx.x;
    const int CH = (N_NODES + 1023) / 1024;   // 49
    const int base = t * CH;
    int s = 0;
    for (int i = 0; i < CH; ++i) {
        int idx = base + i;
        if (idx < N_NODES) s += deg[idx];
    }
    sums[t] = s;
    __syncthreads();
    for (int d = 1; d < 1024; d <<= 1) {
        int v = 0;
        if (t >= d) v = sums[t - d];
        __syncthreads();
        if (t >= d) sums[t] += v;
        __syncthreads();
    }
    int run = (t == 0) ? 0 : sums[t - 1];     // exclusive prefix of this chunk
    for (int i = 0; i < CH; ++i) {
        int idx = base + i;
        if (idx < N_NODES) {
            off[idx] = run;
            cursor[idx] = run;
            run += deg[idx];
        }
    }
    if (t == 1023) off[N_NODES] = sums[1023];
}

// ---------------- CSR build: fill src lists ----------------
__global__ __launch_bounds__(256) void fill_k(const int* __restrict__ ei,
                                              int* __restrict__ cursor, int* __restrict__ csr)
{
    int e = blockIdx.x * 256 + threadIdx.x;
    if (e < N_EDGES) {
        int dst = ei[N_EDGES + e];
        int p = atomicAdd(&cursor[dst], 1);
        csr[p] = ei[e];
    }
}

// ---------------- gather aggregation: out[n] = h[n] + sum_{e: dst=n} h[src] ----------------
// one wave per node; lane owns 8 consecutive floats
__global__ __launch_bounds__(256) void aggregate_k(
    const int* __restrict__ off, const int* __restrict__ csr,
    const float* __restrict__ h, int hstride, float* __restrict__ outb)
{
    int n = blockIdx.x * 4 + (threadIdx.x >> 6);
    if (n >= N_NODES) return;
    int lane = threadIdx.x & 63;
    int c = lane * 8;

    const float* hp = h + (size_t)n * hstride + c;
    float acc[8];
    *(float4*)&acc[0] = *(const float4*)hp;
    *(float4*)&acc[4] = *(const float4*)(hp + 4);

    int e0 = off[n], e1 = off[n + 1];
    for (int e = e0; e < e1; ++e) {
        int src = csr[e];
        const float* sp = h + (size_t)src * hstride + c;
        float4 a = *(const float4*)sp;
        float4 b = *(const float4*)(sp + 4);
        acc[0] += a.x; acc[1] += a.y; acc[2] += a.z; acc[3] += a.w;
        acc[4] += b.x; acc[5] += b.y; acc[6] += b.z; acc[7] += b.w;
    }
    float* op = outb + (size_t)n * DIM + c;
    *(float4*)op = *(const float4*)&acc[0];
    *(float4*)(op + 4) = *(const float4*)&acc[4];
}

// ---------------- fused GEMM: C = leaky(A @ B + bias) ----------------
// 128x128 tile, K-step 16, 256 threads (16x16), 8x8 accum per thread.
__global__ __launch_bounds__(256) void gemm_k(
    const float* __restrict__ A1, int lda1,
    const float* __restrict__ B,         // [DIM][DIM] row-major
    const float* __restrict__ bias,      // [DIM]
    float* __restrict__ C, int ldc, int M)
{
    __shared__ float As[16][132];        // [k][m], +4 pad
    __shared__ float Bs[16][128];        // [k][n]
    const int tid = threadIdx.x;
    const int tx = tid & 15, ty = tid >> 4;
    const int row0 = blockIdx.x * 128;
    const int col0 = blockIdx.y * 128;

    float acc[8][8];
#pragma unroll
    for (int i = 0; i < 8; ++i)
#pragma unroll
        for (int j = 0; j < 8; ++j) acc[i][j] = 0.f;

    const int aRow = tid >> 2;           // 0..63
    const int aCol = (tid & 3) << 2;     // 0,4,8,12
    const int bRow = tid >> 5;           // 0..7
    const int bCol = (tid & 31) << 2;    // 0..124

    for (int k0 = 0; k0 < DIM; k0 += 16) {
#pragma unroll
        for (int half = 0; half < 2; ++half) {
            int r = aRow + half * 64;
            int grow = row0 + r;
            float4 v = make_float4(0.f, 0.f, 0.f, 0.f);
            if (grow < M) v = *(const float4*)(A1 + (size_t)grow * lda1 + k0 + aCol);
            As[aCol + 0][r] = v.x; As[aCol + 1][r] = v.y;
            As[aCol + 2][r] = v.z; As[aCol + 3][r] = v.w;
        }
#pragma unroll
        for (int half = 0; half < 2; ++half) {
            int kr = bRow + half * 8;
            *(float4*)&Bs[kr][bCol] =
                *(const float4*)(B + (size_t)(k0 + kr) * DIM + col0 + bCol);
        }
        __syncthreads();
#pragma unroll
        for (int k = 0; k < 16; ++k) {
            float a[8], b[8];
            *(float4*)&a[0] = *(const float4*)&As[k][ty * 8];
            *(float4*)&a[4] = *(const float4*)&As[k][ty * 8 + 4];
            *(float4*)&b[0] = *(const float4*)&Bs[k][tx * 8];
            *(float4*)&b[4] = *(const float4*)&Bs[k][tx * 8 + 4];
#pragma unroll
            for (int i = 0; i < 8; ++i)
#pragma unroll
                for (int j = 0; j < 8; ++j)
                    acc[i][j] = fmaf(a[i], b[j], acc[i][j]);
        }
        __syncthreads();
    }

    const int cc = col0 + tx * 8;
    float bb[8];
    *(float4*)&bb[0] = *(const float4*)(bias + cc);
    *(float4*)&bb[4] = *(const float4*)(bias + cc + 4);
#pragma unroll
    for (int i = 0; i < 8; ++i) {
        int grow = row0 + ty * 8 + i;
        if (grow < M) {
            float o[8];
#pragma unroll
            for (int j = 0; j < 8; ++j) o[j] = leaky(acc[i][j] + bb[j]);
            *(float4*)(C + (size_t)grow * ldc + cc) = *(float4*)&o[0];
            *(float4*)(C + (size_t)grow * ldc + cc + 4) = *(float4*)&o[4];
        }
    }
}

// ------- NodeNorm (in place) + per-block BatchNorm partial stats -------
__global__ __launch_bounds__(256) void nodenorm_k(
    float* __restrict__ z, float* __restrict__ partials /* [gridDim.x][1024] */)
{
    __shared__ float part[1024];
    for (int t = threadIdx.x; t < 1024; t += 256) part[t] = 0.f;
    __syncthreads();

    int wave = blockIdx.x * 4 + (threadIdx.x >> 6);
    int lane = threadIdx.x & 63;
    int nw = gridDim.x * 4;
    int per = (N_NODES + nw - 1) / nw;
    int r0 = wave * per;
    int r1 = min(N_NODES, r0 + per);

    float cs[8] = {0, 0, 0, 0, 0, 0, 0, 0};
    float cq[8] = {0, 0, 0, 0, 0, 0, 0, 0};

    for (int r = r0; r < r1; ++r) {
        float* p = z + (size_t)r * DIM;
        float4 a = *(const float4*)(p + lane * 4);
        float4 b = *(const float4*)(p + 256 + lane * 4);
        float s = a.x + a.y + a.z + a.w + b.x + b.y + b.z + b.w;
        float q = a.x * a.x + a.y * a.y + a.z * a.z + a.w * a.w
                + b.x * b.x + b.y * b.y + b.z * b.z + b.w * b.w;
#pragma unroll
        for (int off = 32; off; off >>= 1) {
            s += __shfl_xor(s, off);
            q += __shfl_xor(q, off);
        }
        float mean = s * (1.f / DIM);
        float var = q * (1.f / DIM) - mean * mean;
        float rs = rsqrtf(var + EPS_F);
        a.x = (a.x - mean) * rs; a.y = (a.y - mean) * rs;
        a.z = (a.z - mean) * rs; a.w = (a.w - mean) * rs;
        b.x = (b.x - mean) * rs; b.y = (b.y - mean) * rs;
        b.z = (b.z - mean) * rs; b.w = (b.w - mean) * rs;
        *(float4*)(p + lane * 4) = a;
        *(float4*)(p + 256 + lane * 4) = b;
        cs[0] += a.x; cs[1] += a.y; cs[2] += a.z; cs[3] += a.w;
        cs[4] += b.x; cs[5] += b.y; cs[6] += b.z; cs[7] += b.w;
        cq[0] += a.x * a.x; cq[1] += a.y * a.y; cq[2] += a.z * a.z; cq[3] += a.w * a.w;
        cq[4] += b.x * b.x; cq[5] += b.y * b.y; cq[6] += b.z * b.z; cq[7] += b.w * b.w;
    }
#pragma unroll
    for (int i = 0; i < 4; ++i) {
        atomicAdd(&part[lane * 4 + i], cs[i]);
        atomicAdd(&part[256 + lane * 4 + i], cs[4 + i]);
        atomicAdd(&part[512 + lane * 4 + i], cq[i]);
        atomicAdd(&part[768 + lane * 4 + i], cq[4 + i]);
    }
    __syncthreads();
    float* dst = partials + (size_t)blockIdx.x * 1024;
    *(float4*)(dst + threadIdx.x * 4) = *(const float4*)&part[threadIdx.x * 4];
}

// ------- BatchNorm finalize: scale/shift per column -------
__global__ void bn_finalize_k(
    const float* __restrict__ partials, int nblocks,
    const float* __restrict__ gamma, const float* __restrict__ beta,
    float* __restrict__ sc, float* __restrict__ sh)
{
    int c = blockIdx.x * blockDim.x + threadIdx.x;
    if (c >= DIM) return;
    float s = 0.f, q = 0.f;
#pragma unroll 8
    for (int b = 0; b < nblocks; ++b) {
        s += partials[(size_t)b * 1024 + c];
        q += partials[(size_t)b * 1024 + 512 + c];
    }
    float mean = s * (1.f / N_NODES);
    float var = q * (1.f / N_NODES) - mean * mean;
    float sf = gamma[c] * rsqrtf(var + EPS_F);
    sc[c] = sf;
    sh[c] = beta[c] - mean * sf;
}

// ------- BatchNorm apply + x_local write + sorted-segment pooling -------
__global__ __launch_bounds__(256) void apply_pool_k(
    const float* __restrict__ z, const float* __restrict__ sc, const float* __restrict__ sh,
    const int* __restrict__ batch,
    float* __restrict__ xloc,   // d_out local base + layer*DIM, row stride 2048
    float* __restrict__ xglob)  // d_out global base + layer*DIM, row stride 2048
{
    int wave = blockIdx.x * 4 + (threadIdx.x >> 6);
    int lane = threadIdx.x & 63;
    int nw = gridDim.x * 4;
    int per = (N_NODES + nw - 1) / nw;
    int r0 = wave * per;
    int r1 = min(N_NODES, r0 + per);
    if (r0 >= r1) return;

    float4 s0 = *(const float4*)(sc + lane * 4);
    float4 s1 = *(const float4*)(sc + 256 + lane * 4);
    float4 t0 = *(const float4*)(sh + lane * 4);
    float4 t1 = *(const float4*)(sh + 256 + lane * 4);

    float pa[8] = {0, 0, 0, 0, 0, 0, 0, 0};
    int curg = batch[r0];
    const int LD = N_LAYERS * DIM; // 2048

    for (int r = r0; r < r1; ++r) {
        int g = batch[r];
        if (g != curg) {
#pragma unroll
            for (int i = 0; i < 4; ++i) {
                atomicAdd(xglob + (size_t)curg * LD + lane * 4 + i, pa[i]);
                atomicAdd(xglob + (size_t)curg * LD + 256 + lane * 4 + i, pa[4 + i]);
                pa[i] = 0.f; pa[4 + i] = 0.f;
            }
            curg = g;
        }
        const float* p = z + (size_t)r * DIM;
        float4 a = *(const float4*)(p + lane * 4);
        float4 b = *(const float4*)(p + 256 + lane * 4);
        a.x = fmaf(a.x, s0.x, t0.x); a.y = fmaf(a.y, s0.y, t0.y);
        a.z = fmaf(a.z, s0.z, t0.z); a.w = fmaf(a.w, s0.w, t0.w);
        b.x = fmaf(b.x, s1.x, t1.x); b.y = fmaf(b.y, s1.y, t1.y);
        b.z = fmaf(b.z, s1.z, t1.z); b.w = fmaf(b.w, s1.w, t1.w);
        *(float4*)(xloc + (size_t)r * LD + lane * 4) = a;
        *(float4*)(xloc + (size_t)r * LD + 256 + lane * 4) = b;
        pa[0] += a.x; pa[1] += a.y; pa[2] += a.z; pa[3] += a.w;
        pa[4] += b.x; pa[5] += b.y; pa[6] += b.z; pa[7] += b.w;
    }
#pragma unroll
    for (int i = 0; i < 4; ++i) {
        atomicAdd(xglob + (size_t)curg * LD + lane * 4 + i, pa[i]);
        atomicAdd(xglob + (size_t)curg * LD + 256 + lane * 4 + i, pa[4 + i]);
    }
}

extern "C" void kernel_launch(void* const* d_in, const int* in_sizes, int n_in,
                              void* d_out, int out_size, void* d_ws, size_t ws_size,
                              hipStream_t stream)
{
    const float* x     = (const float*)d_in[0];
    const int*   ei    = (const int*)d_in[1];
    const int*   batch = (const int*)d_in[2];
    const float* W1    = (const float*)d_in[3];
    const float* b1    = (const float*)d_in[4];
    const float* W2    = (const float*)d_in[5];
    const float* b2    = (const float*)d_in[6];
    const float* gamma = (const float*)d_in[7];
    const float* beta  = (const float*)d_in[8];

    float* out = (float*)d_out;
    const size_t XG = (size_t)N_GRAPHS * N_LAYERS * DIM;  // 1,024,000
    float* xglob_base = out;
    float* xloc_base  = out + XG;

    const size_t NODE_BUF = (size_t)N_NODES * DIM;        // 25.6M floats
    const int NN_BLOCKS = 256;
    float* bufA     = (float*)d_ws;                        // aggr+self → z2/z3
    float* bufB     = bufA + NODE_BUF;                     // z1
    float* partials = bufB + NODE_BUF;                     // [NN_BLOCKS][1024]
    float* sc       = partials + (size_t)NN_BLOCKS * 1024;
    float* sh       = sc + DIM;
    int*   deg      = (int*)(sh + DIM);
    int*   off      = deg + N_NODES;                       // N_NODES+1
    int*   cursor   = off + N_NODES + 1;
    int*   csr      = cursor + N_NODES;                    // N_EDGES

    hipMemsetAsync(xglob_base, 0, XG * sizeof(float), stream);
    hipMemsetAsync(deg, 0, N_NODES * sizeof(int), stream);

    // ---- CSR build (edge list is layer-invariant: build once per launch) ----
    hist_k<<<(N_EDGES + 255) / 256, 256, 0, stream>>>(ei, deg);
    scan_k<<<1, 1024, 0, stream>>>(deg, off, cursor);
    fill_k<<<(N_EDGES + 255) / 256, 256, 0, stream>>>(ei, cursor, csr);

    for (int i = 0; i < N_LAYERS; ++i) {
        const float* h;
        int hstride;
        if (i == 0) { h = x; hstride = DIM; }
        else        { h = xloc_base + (size_t)(i - 1) * DIM; hstride = N_LAYERS * DIM; }

        aggregate_k<<<(N_NODES + 3) / 4, 256, 0, stream>>>(off, csr, h, hstride, bufA);

        gemm_k<<<dim3((N_NODES + 127) / 128, DIM / 128), 256, 0, stream>>>(
            bufA, DIM, W1 + (size_t)i * DIM * DIM, b1 + (size_t)i * DIM,
            bufB, DIM, N_NODES);

        gemm_k<<<dim3((N_NODES + 127) / 128, DIM / 128), 256, 0, stream>>>(
            bufB, DIM, W2 + (size_t)i * DIM * DIM, b2 + (size_t)i * DIM,
            bufA, DIM, N_NODES);

        nodenorm_k<<<NN_BLOCKS, 256, 0, stream>>>(bufA, partials);

        bn_finalize_k<<<2, 256, 0, stream>>>(partials, NN_BLOCKS,
            gamma + (size_t)i * DIM, beta + (size_t)i * DIM, sc, sh);

        apply_pool_k<<<512, 256, 0, stream>>>(bufA, sc, sh, batch,
            xloc_base + (size_t)i * DIM, xglob_base + (size_t)i * DIM);
    }
}